// Round 7
// baseline (513.034 us; speedup 1.0000x reference)
//
#include <hip/hip_runtime.h>
#include <hip/hip_bf16.h>

typedef unsigned short u16;
typedef unsigned int   u32;
typedef __bf16 bf16x8 __attribute__((ext_vector_type(8)));
typedef u16    u16x8  __attribute__((ext_vector_type(8)));
typedef float  f32x4  __attribute__((ext_vector_type(4)));

#define DI static __device__ __forceinline__

DI float b2f(u16 u){ union { u32 i; float f; } c; c.i = ((u32)u) << 16; return c.f; }
DI u16 f2b(float f){
  __hip_bfloat16 h = __float2bfloat16(f);
  union { __hip_bfloat16 b; u16 u; } c; c.b = h; return c.u;
}
DI float eluf(float x){ return x > 0.f ? x : (__expf(x) - 1.f); }
DI float sigf(float x){ return 1.f / (1.f + __expf(-x)); }
DI f32x4 mfma16(bf16x8 a, bf16x8 b, f32x4 c){
  return __builtin_amdgcn_mfma_f32_16x16x32_bf16(a, b, c, 0, 0, 0);
}
DI u32 pk2(float lo, float hi){
  __hip_bfloat162 p = __float22bfloat162_rn(make_float2(lo, hi));
  union { __hip_bfloat162 b; u32 u; } c; c.b = p; return c.u;
}
DI bf16x8 cvt8f(float4 a, float4 b){
  union { u32 w[4]; u16x8 v; } t;
  t.w[0] = pk2(a.x, a.y); t.w[1] = pk2(a.z, a.w);
  t.w[2] = pk2(b.x, b.y); t.w[3] = pk2(b.z, b.w);
  return __builtin_bit_cast(bf16x8, t.v);
}
DI bf16x8 ldb(const u16* p){ return *(const bf16x8*)p; }

// ---------------------------------------------------------------------------
// Pack all weights (fp32 -> bf16) into MFMA B-fragment order:
//   frag[tile][kc][lane(64)][8], element = W[k = kc*32 + (lane>>4)*8 + j]
//                                          [n = nb*16 + (lane&15)]
// Ranges (8-elem groups): pW1 34816 | pF1 32768 | pSk 32768 | pF2 131072 | pGa 131072
// ---------------------------------------------------------------------------
__global__ __launch_bounds__(256) void k_pack(
    const float* __restrict__ wfc1, const float* __restrict__ wskip,
    const float* __restrict__ vfc1, const float* __restrict__ vfc2,
    const float* __restrict__ vgate, const float* __restrict__ vskip,
    u16* __restrict__ pW1, u16* __restrict__ pF1, u16* __restrict__ pSk,
    u16* __restrict__ pF2, u16* __restrict__ pGa)
{
  const int g = blockIdx.x * 256 + threadIdx.x;   // 362496 total
  float v8[8];
  u16* dst;
  if (g < 34816){                 // pW1: nb 0..16, kc 0..31 (K=1024)
    int idx = g, lane = idx & 63, kc = (idx >> 6) & 31, nb = idx >> 11;
    int ln = lane & 15, q = lane >> 4;
    #pragma unroll
    for (int j = 0; j < 8; j++){
      int k = kc * 32 + q * 8 + j;
      v8[j] = (nb < 16) ? wfc1[(size_t)k * 256 + nb * 16 + ln]
                        : wskip[(size_t)k * 16 + ln];
    }
    dst = pW1 + (size_t)idx * 8;
  } else if (g < 67584){          // pF1: v, nb 0..15, kc 0..1 (K=64)
    int idx = g - 34816, lane = idx & 63, kc = (idx >> 6) & 1, nb = (idx >> 7) & 15, v = idx >> 11;
    int ln = lane & 15, q = lane >> 4;
    #pragma unroll
    for (int j = 0; j < 8; j++){
      int k = kc * 32 + q * 8 + j;
      v8[j] = vfc1[((size_t)v * 64 + k) * 256 + nb * 16 + ln];
    }
    dst = pF1 + (size_t)idx * 8;
  } else if (g < 100352){         // pSk
    int idx = g - 67584, lane = idx & 63, kc = (idx >> 6) & 1, nb = (idx >> 7) & 15, v = idx >> 11;
    int ln = lane & 15, q = lane >> 4;
    #pragma unroll
    for (int j = 0; j < 8; j++){
      int k = kc * 32 + q * 8 + j;
      v8[j] = vskip[((size_t)v * 64 + k) * 256 + nb * 16 + ln];
    }
    dst = pSk + (size_t)idx * 8;
  } else if (g < 231424){         // pF2: v, nb, kc 0..7 (K=256)
    int idx = g - 100352, lane = idx & 63, kc = (idx >> 6) & 7, nb = (idx >> 9) & 15, v = idx >> 13;
    int ln = lane & 15, q = lane >> 4;
    #pragma unroll
    for (int j = 0; j < 8; j++){
      int k = kc * 32 + q * 8 + j;
      v8[j] = vfc2[((size_t)v * 256 + k) * 256 + nb * 16 + ln];
    }
    dst = pF2 + (size_t)idx * 8;
  } else {                        // pGa
    int idx = g - 231424, lane = idx & 63, kc = (idx >> 6) & 7, nb = (idx >> 9) & 15, v = idx >> 13;
    int ln = lane & 15, q = lane >> 4;
    #pragma unroll
    for (int j = 0; j < 8; j++){
      int k = kc * 32 + q * 8 + j;
      v8[j] = vgate[((size_t)v * 256 + k) * 256 + nb * 16 + ln];
    }
    dst = pGa + (size_t)idx * 8;
  }
  u16x8 t;
  #pragma unroll
  for (int j = 0; j < 8; j++) t[j] = f2b(v8[j]);
  *(uint4*)dst = __builtin_bit_cast(uint4, t);
}

// ---------------------------------------------------------------------------
// Fused VSN kernel: weight GRN (softmax weights -> LDS) + per-variable GRNs.
// 512 blocks x 32 rows, 512 threads = 8 waves. Wave wid owns nb {2w, 2w+1}
// (wave 7 additionally nb16 = skip cols in weight phase), row-tiles mb 0..1.
// Weights streamed directly from packed global fragments. hv/yv in separate
// LDS buffers -> 2 barriers per v. LDS ~35.8 KB -> 2 blocks/CU.
// ---------------------------------------------------------------------------
__global__ __launch_bounds__(512) void k_vsn(
    const float* __restrict__ x, const u16* __restrict__ pW1,
    const u16* __restrict__ pF1, const u16* __restrict__ pSk,
    const u16* __restrict__ pF2, const u16* __restrict__ pGa,
    const float* __restrict__ wb1, const float* __restrict__ W2,
    const float* __restrict__ wb2, const float* __restrict__ Wg,
    const float* __restrict__ wbg, const float* __restrict__ wbs,
    const float* __restrict__ b1, const float* __restrict__ b2,
    const float* __restrict__ bg, const float* __restrict__ bs,
    float* __restrict__ out)
{
  __shared__ u16 sHh[32 * 264];      // h / hv (bf16)
  __shared__ u16 sHy[32 * 264];      // yv (bf16); weight-phase overlay: sR/sY/sG
  __shared__ float sWt[32 * 16];     // softmax weights fp32
  float* sR = (float*)sHy;           // [32][16] res
  float* sY = sR + 512;              // [32][16] y
  float* sG = sY + 512;              // [32][16] gate

  const int tid  = threadIdx.x;
  const int lane = tid & 63;
  const int wid  = tid >> 6;
  const int ln   = lane & 15;
  const int q    = lane >> 4;
  const int row0 = blockIdx.x * 32;
  const int nb0  = wid * 2;
  const int ncnt = (wid == 7) ? 3 : 2;

  // ================= weight GRN =================
  {
    f32x4 acc[2][3];
    #pragma unroll
    for (int mb = 0; mb < 2; mb++)
      #pragma unroll
      for (int i = 0; i < 3; i++){ acc[mb][i][0]=0.f; acc[mb][i][1]=0.f; acc[mb][i][2]=0.f; acc[mb][i][3]=0.f; }

    #pragma unroll 4
    for (int kc = 0; kc < 32; kc++){
      bf16x8 a[2];
      #pragma unroll
      for (int mb = 0; mb < 2; mb++){
        const float* xp = &x[(size_t)(row0 + mb * 16 + ln) * 1024 + kc * 32 + q * 8];
        a[mb] = cvt8f(*(const float4*)xp, *(const float4*)(xp + 4));
      }
      #pragma unroll
      for (int i = 0; i < 3; i++){
        if (i < ncnt){
          bf16x8 b = ldb(&pW1[(size_t)((nb0 + i) * 32 + kc) * 512 + lane * 8]);
          #pragma unroll
          for (int mb = 0; mb < 2; mb++) acc[mb][i] = mfma16(a[mb], b, acc[mb][i]);
        }
      }
    }

    // h -> sHh (bf16), res -> sR (fp32)
    #pragma unroll
    for (int i = 0; i < 3; i++){
      if (i < ncnt){
        int nb = nb0 + i;
        int col = nb * 16 + ln;
        float vb = (nb < 16) ? wb1[col] : wbs[ln];
        #pragma unroll
        for (int mb = 0; mb < 2; mb++){
          #pragma unroll
          for (int r = 0; r < 4; r++){
            int lr = mb * 16 + q * 4 + r;
            float v = acc[mb][i][r] + vb;
            if (nb < 16) sHh[lr * 264 + col] = f2b(eluf(v));
            else         sR[lr * 16 + ln] = v;
          }
        }
      }
    }
    __syncthreads();

    // y = h @ W2 + b2 : thread r = tid>>4 (0..31), col j = tid&15 (W2 streamed)
    {
      int r = tid >> 4, j = tid & 15;
      float a = wb2[j];
      #pragma unroll 8
      for (int k = 0; k < 256; k++)
        a += b2f(sHh[r * 264 + k]) * W2[k * 16 + j];
      sY[r * 16 + j] = a;
    }
    __syncthreads();

    // gate = sigmoid(y @ Wg + bg)
    {
      int r = tid >> 4, j = tid & 15;
      float g = wbg[j];
      #pragma unroll
      for (int k = 0; k < 16; k++)
        g += sY[r * 16 + k] * Wg[k * 16 + j];
      sG[r * 16 + j] = sigf(g);
    }
    __syncthreads();

    // softmax over 16 -> sWt
    if (tid < 32){
      int r = tid;
      float l[16]; float m = -1e30f;
      #pragma unroll
      for (int j = 0; j < 16; j++){
        float v = sR[r * 16 + j] + sG[r * 16 + j] * sY[r * 16 + j];
        l[j] = v; m = fmaxf(m, v);
      }
      float s = 0.f;
      #pragma unroll
      for (int j = 0; j < 16; j++){ l[j] = __expf(l[j] - m); s += l[j]; }
      float inv = 1.f / s;
      #pragma unroll
      for (int j = 0; j < 16; j++) sWt[r * 16 + j] = l[j] * inv;
    }
    __syncthreads();   // sWt visible; sR/sY/sG dead; sHh free after v=0 hv write
  }

  // ================= per-variable GRNs =================
  f32x4 z[2][2];
  #pragma unroll
  for (int mb = 0; mb < 2; mb++)
    #pragma unroll
    for (int i = 0; i < 2; i++){ z[mb][i][0]=0.f; z[mb][i][1]=0.f; z[mb][i][2]=0.f; z[mb][i][3]=0.f; }

  for (int v = 0; v < 16; v++){
    bf16x8 a0[2], a1[2];
    #pragma unroll
    for (int mb = 0; mb < 2; mb++){
      const float* xp = &x[(size_t)(row0 + mb * 16 + ln) * 1024 + v * 64 + q * 8];
      a0[mb] = cvt8f(*(const float4*)xp, *(const float4*)(xp + 4));
      a1[mb] = cvt8f(*(const float4*)(xp + 32), *(const float4*)(xp + 36));
    }
    float wv[2][4];
    #pragma unroll
    for (int mb = 0; mb < 2; mb++)
      #pragma unroll
      for (int r = 0; r < 4; r++) wv[mb][r] = sWt[(mb * 16 + q * 4 + r) * 16 + v];

    // ---- phase 1a: hv = elu(Xv @ W1v + b1) -> sHh
    f32x4 hacc[2][2];
    #pragma unroll
    for (int mb = 0; mb < 2; mb++)
      #pragma unroll
      for (int i = 0; i < 2; i++){ hacc[mb][i][0]=0.f; hacc[mb][i][1]=0.f; hacc[mb][i][2]=0.f; hacc[mb][i][3]=0.f; }
    #pragma unroll
    for (int ks = 0; ks < 2; ks++){
      bf16x8 B0 = ldb(&pF1[(size_t)((v * 16 + nb0) * 2 + ks) * 512 + lane * 8]);
      bf16x8 B1 = ldb(&pF1[(size_t)((v * 16 + nb0 + 1) * 2 + ks) * 512 + lane * 8]);
      #pragma unroll
      for (int mb = 0; mb < 2; mb++){
        bf16x8 a = ks ? a1[mb] : a0[mb];
        hacc[mb][0] = mfma16(a, B0, hacc[mb][0]);
        hacc[mb][1] = mfma16(a, B1, hacc[mb][1]);
      }
    }
    #pragma unroll
    for (int i = 0; i < 2; i++){
      int col = (nb0 + i) * 16 + ln;
      float vb = b1[v * 256 + col];
      #pragma unroll
      for (int mb = 0; mb < 2; mb++)
        #pragma unroll
        for (int r = 0; r < 4; r++)
          sHh[(mb * 16 + q * 4 + r) * 264 + col] = f2b(eluf(hacc[mb][i][r] + vb));
    }

    // ---- phase 1b: rv = Xv @ Wsv + bs ; z += wv * rv
    f32x4 racc[2][2];
    #pragma unroll
    for (int mb = 0; mb < 2; mb++)
      #pragma unroll
      for (int i = 0; i < 2; i++){ racc[mb][i][0]=0.f; racc[mb][i][1]=0.f; racc[mb][i][2]=0.f; racc[mb][i][3]=0.f; }
    #pragma unroll
    for (int ks = 0; ks < 2; ks++){
      bf16x8 B0 = ldb(&pSk[(size_t)((v * 16 + nb0) * 2 + ks) * 512 + lane * 8]);
      bf16x8 B1 = ldb(&pSk[(size_t)((v * 16 + nb0 + 1) * 2 + ks) * 512 + lane * 8]);
      #pragma unroll
      for (int mb = 0; mb < 2; mb++){
        bf16x8 a = ks ? a1[mb] : a0[mb];
        racc[mb][0] = mfma16(a, B0, racc[mb][0]);
        racc[mb][1] = mfma16(a, B1, racc[mb][1]);
      }
    }
    #pragma unroll
    for (int i = 0; i < 2; i++){
      float vb = bs[v * 256 + (nb0 + i) * 16 + ln];
      #pragma unroll
      for (int mb = 0; mb < 2; mb++)
        #pragma unroll
        for (int r = 0; r < 4; r++) z[mb][i][r] += wv[mb][r] * (racc[mb][i][r] + vb);
    }
    __syncthreads();   // (A) hv visible; prev-v yv reads all done

    // ---- phase 2: yv = hv @ W2v + b2 -> sHy
    f32x4 yacc[2][2];
    #pragma unroll
    for (int mb = 0; mb < 2; mb++)
      #pragma unroll
      for (int i = 0; i < 2; i++){ yacc[mb][i][0]=0.f; yacc[mb][i][1]=0.f; yacc[mb][i][2]=0.f; yacc[mb][i][3]=0.f; }
    #pragma unroll 4
    for (int kc = 0; kc < 8; kc++){
      bf16x8 B0 = ldb(&pF2[(size_t)((v * 16 + nb0) * 8 + kc) * 512 + lane * 8]);
      bf16x8 B1 = ldb(&pF2[(size_t)((v * 16 + nb0 + 1) * 8 + kc) * 512 + lane * 8]);
      #pragma unroll
      for (int mb = 0; mb < 2; mb++){
        bf16x8 ah = *(const bf16x8*)&sHh[(mb * 16 + ln) * 264 + kc * 32 + q * 8];
        yacc[mb][0] = mfma16(ah, B0, yacc[mb][0]);
        yacc[mb][1] = mfma16(ah, B1, yacc[mb][1]);
      }
    }
    f32x4 ysave[2][2];
    #pragma unroll
    for (int i = 0; i < 2; i++){
      int col = (nb0 + i) * 16 + ln;
      float vb = b2[v * 256 + col];
      #pragma unroll
      for (int mb = 0; mb < 2; mb++)
        #pragma unroll
        for (int r = 0; r < 4; r++){
          float yy = yacc[mb][i][r] + vb;
          ysave[mb][i][r] = yy;
          sHy[(mb * 16 + q * 4 + r) * 264 + col] = f2b(yy);
        }
    }
    __syncthreads();   // (B) yv visible; all hv reads done

    // ---- phase 3: gv = sigmoid(yv @ Wgv + bg); z += wv * gv * yv
    f32x4 gacc[2][2];
    #pragma unroll
    for (int mb = 0; mb < 2; mb++)
      #pragma unroll
      for (int i = 0; i < 2; i++){ gacc[mb][i][0]=0.f; gacc[mb][i][1]=0.f; gacc[mb][i][2]=0.f; gacc[mb][i][3]=0.f; }
    #pragma unroll 4
    for (int kc = 0; kc < 8; kc++){
      bf16x8 B0 = ldb(&pGa[(size_t)((v * 16 + nb0) * 8 + kc) * 512 + lane * 8]);
      bf16x8 B1 = ldb(&pGa[(size_t)((v * 16 + nb0 + 1) * 8 + kc) * 512 + lane * 8]);
      #pragma unroll
      for (int mb = 0; mb < 2; mb++){
        bf16x8 ah = *(const bf16x8*)&sHy[(mb * 16 + ln) * 264 + kc * 32 + q * 8];
        gacc[mb][0] = mfma16(ah, B0, gacc[mb][0]);
        gacc[mb][1] = mfma16(ah, B1, gacc[mb][1]);
      }
    }
    #pragma unroll
    for (int i = 0; i < 2; i++){
      float vb = bg[v * 256 + (nb0 + i) * 16 + ln];
      #pragma unroll
      for (int mb = 0; mb < 2; mb++)
        #pragma unroll
        for (int r = 0; r < 4; r++)
          z[mb][i][r] += wv[mb][r] * sigf(gacc[mb][i][r] + vb) * ysave[mb][i][r];
    }
    // no trailing barrier: next v's (A) barrier protects sHh/sHy reuse
  }

  // store z -> out (fp32), C/D layout: row = q*4+reg, col = lane&15
  #pragma unroll
  for (int i = 0; i < 2; i++){
    int col = (nb0 + i) * 16 + ln;
    #pragma unroll
    for (int mb = 0; mb < 2; mb++)
      #pragma unroll
      for (int r = 0; r < 4; r++)
        out[(size_t)(row0 + mb * 16 + q * 4 + r) * 256 + col] = z[mb][i][r];
  }
}

// ---------------------------------------------------------------------------
extern "C" void kernel_launch(void* const* d_in, const int* in_sizes, int n_in,
                              void* d_out, int out_size, void* d_ws, size_t ws_size,
                              hipStream_t stream)
{
  const float* x     = (const float*)d_in[0];
  const float* wfc1w = (const float*)d_in[1];
  const float* wfc1b = (const float*)d_in[2];
  const float* wfc2w = (const float*)d_in[3];
  const float* wfc2b = (const float*)d_in[4];
  const float* wgw   = (const float*)d_in[5];
  const float* wgb   = (const float*)d_in[6];
  const float* wsw   = (const float*)d_in[7];
  const float* wsb   = (const float*)d_in[8];
  const float* vfc1w = (const float*)d_in[9];
  const float* vfc1b = (const float*)d_in[10];
  const float* vfc2w = (const float*)d_in[11];
  const float* vfc2b = (const float*)d_in[12];
  const float* vgw   = (const float*)d_in[13];
  const float* vgb   = (const float*)d_in[14];
  const float* vsw   = (const float*)d_in[15];
  const float* vsb   = (const float*)d_in[16];

  u16* ws   = (u16*)d_ws;
  u16* pW1  = ws;                      // 278528 u16
  u16* pF1  = pW1 + 278528;            // 262144
  u16* pSk  = pF1 + 262144;            // 262144
  u16* pF2  = pSk + 262144;            // 1048576
  u16* pGa  = pF2 + 1048576;           // 1048576

  k_pack<<<dim3(1416), dim3(256), 0, stream>>>(
      wfc1w, wsw, vfc1w, vfc2w, vgw, vsw, pW1, pF1, pSk, pF2, pGa);

  k_vsn<<<dim3(512), dim3(512), 0, stream>>>(
      x, pW1, pF1, pSk, pF2, pGa,
      wfc1b, wfc2w, wfc2b, wgw, wgb, wsb,
      vfc1b, vfc2b, vgb, vsb, (float*)d_out);
}